// Round 5
// baseline (425.754 us; speedup 1.0000x reference)
//
#include <hip/hip_runtime.h>
#include <hip/hip_bf16.h>

#define BATCH 8
#define CH    64
#define HH    112
#define WW    112
#define HW    (HH * WW)          // 12544
#define NP    (BATCH * HW)       // 100352 pixels
#define TAPS  25
#define MIDC  256
#define OPAD  28                 // o-dim padded 25 -> 28 in LDS only
#define GROW  24                 // global main row: 6 x float4 (96 B, aligned)
#define CROW  OPAD               // LDS floats per (tap, ch) weight row
#define TBLK  (CH * CROW + 16)   // floats per staged tap (incl. 4-float cg skew)
#define TCH   3                  // taps per LDS chunk (21,696 B)

typedef float vf4 __attribute__((ext_vector_type(4)));

// ---------------------------------------------------------------------------
// Kernel A: weff[o][ch][tap] folding, stored split to fit ws_size:
//   weff_main[tap][ch][24]  (o = 0..23, 6 x float4 per row)
//   weff_tail[tap][ch]      (o = 24)
// Total ws use = 38400 + 1600 + 25 floats = 160,100 B (proven footprint).
// Thread t = ctap: w1 read exactly once, coalesced; w2 transposed in LDS.
// ---------------------------------------------------------------------------
__global__ __launch_bounds__(256) void weff_kernel(
    const float* __restrict__ w1, const float* __restrict__ b1,
    const float* __restrict__ w2, const float* __restrict__ b2,
    float* __restrict__ weff_main, float* __restrict__ weff_tail,
    float* __restrict__ beff) {
  __shared__ __align__(16) float w2t[MIDC * OPAD];   // [mid][28], pads = 0
  for (int e = threadIdx.x; e < TAPS * MIDC; e += 256) {
    int o = e / MIDC, mid = e % MIDC;                // e == w2 flat index
    w2t[mid * OPAD + o] = w2[e];
  }
  for (int e = threadIdx.x; e < MIDC * 3; e += 256)
    w2t[(e / 3) * OPAD + 25 + (e % 3)] = 0.f;
  __syncthreads();

  int t = blockIdx.x * 256 + threadIdx.x;            // ctap
  if (t < CH * TAPS) {
    int c = t / TAPS, tap = t % TAPS;
    vf4 acc[7];
    #pragma unroll
    for (int q = 0; q < 7; ++q) acc[q] = (vf4)0.f;
    const vf4* w2v = (const vf4*)w2t;
    #pragma unroll 4
    for (int mid = 0; mid < MIDC; ++mid) {
      float a = w1[(size_t)mid * (CH * TAPS) + t];   // coalesced
      vf4 av = {a, a, a, a};
      const vf4* row = w2v + mid * 7;
      #pragma unroll
      for (int q = 0; q < 7; ++q) acc[q] += av * row[q];
    }
    vf4* op = (vf4*)(weff_main + ((size_t)tap * CH + c) * GROW);
    #pragma unroll
    for (int q = 0; q < 6; ++q) op[q] = acc[q];      // o = 0..23
    weff_tail[tap * CH + c] = acc[6][0];             // o = 24
  }
  if (blockIdx.x == 0 && threadIdx.x < TAPS) {
    int o = threadIdx.x;
    float bacc = b2[o];
    for (int mid = 0; mid < MIDC; ++mid) bacc += w2t[mid * OPAD + o] * b1[mid];
    beff[o] = bacc;
  }
}

// ---------------------------------------------------------------------------
// Kernel B: lane = (px 0..15, cg 0..3); each lane: 1 pixel x 16 channels.
// Wave covers 16 px x 64 ch (self-contained). Block = 4 waves = 64 px.
// Weights tap-chunked through LDS (28-padded + cg-skewed at stage time;
// conflict-free b128 reads); float4 packed accumulators (v_pk_fma_f32);
// shuffle reduce; register softmax; fused apply. XCD swizzle: blockIdx & 7.
// ---------------------------------------------------------------------------
__global__ __launch_bounds__(256, 6) void picanet_main(
    const float* __restrict__ x, const float* __restrict__ weff_main,
    const float* __restrict__ weff_tail, const float* __restrict__ beff,
    float* __restrict__ out) {
  __shared__ __align__(16) float sw[TCH * TBLK];     // 21,696 B

  const int tid  = threadIdx.x;
  const int lane = tid & 63, wave = tid >> 6;
  const int px = lane & 15, cg = lane >> 4;

  const int b     = blockIdx.x & 7;                  // XCD-aligned image
  const int strip = blockIdx.x >> 3;
  const int hw = strip * 64 + wave * 16 + px;
  const int h = hw / WW, w = hw % WW;

  const float* xc = x + ((size_t)b * CH + cg * 16) * HW;  // lane's ch plane 0
  const int lbase = cg * (16 * CROW + 4);            // skewed cg base in a tap

  // Zero LDS pad slots (o = 25..27 of every row) once; staging never touches
  // them, so the zeros persist across chunks. Visible after first barrier.
  for (int e = tid; e < TCH * CH * 3; e += 256) {
    int tl = e / (CH * 3), r2 = e % (CH * 3);
    int ch = r2 / 3, k = r2 % 3;
    sw[tl * TBLK + ch * CROW + (ch >> 4) * 4 + 25 + k] = 0.f;
  }

  vf4 s4[7];
  #pragma unroll
  for (int q = 0; q < 7; ++q) s4[q] = (vf4)0.f;

  for (int tap0 = 0; tap0 < TAPS; tap0 += TCH) {
    const int tch = (TAPS - tap0 < TCH) ? (TAPS - tap0) : TCH;
    __syncthreads();                                 // protect prior readers
    for (int r = tid; r < tch * CH; r += 256) {      // stage chunk
      int tl = r >> 6, ch = r & 63;
      const float* srow = weff_main + ((size_t)(tap0 + tl) * CH + ch) * GROW;
      float* drow = sw + tl * TBLK + ch * CROW + (ch >> 4) * 4;
      const vf4* src = (const vf4*)srow;
      vf4* dst = (vf4*)drow;
      #pragma unroll
      for (int q = 0; q < 6; ++q) dst[q] = src[q];
      drow[24] = weff_tail[(tap0 + tl) * CH + ch];
    }
    __syncthreads();

    for (int tl = 0; tl < tch; ++tl) {
      int tap = tap0 + tl;
      int i = (tap * 52429) >> 18;                   // tap / 5 (exact, tap<25)
      int j = tap - 5 * i;
      int yy = h + 2 * i - 4, xx = w + 2 * j - 4;
      bool ok = (yy >= 0) & (yy < HH) & (xx >= 0) & (xx < WW);
      int   offt = ok ? yy * WW + xx : 0;
      float mk   = ok ? 1.f : 0.f;

      float xv[16];
      #pragma unroll
      for (int c = 0; c < 16; ++c) xv[c] = xc[(size_t)c * HW + offt];

      const float* wb = sw + tl * TBLK + lbase;
      #pragma unroll
      for (int c = 0; c < 16; ++c) {
        float xm = xv[c] * mk;
        vf4 xs = {xm, xm, xm, xm};
        const vf4* row = (const vf4*)(wb + c * CROW);
        #pragma unroll
        for (int q = 0; q < 7; ++q) s4[q] += xs * row[q];  // v_pk_fma_f32 x2
      }
    }
  }

  // ---- reduce partial logits across cg (lanes px, px+16, px+32, px+48) ----
  #pragma unroll
  for (int q = 0; q < 7; ++q) {
    #pragma unroll
    for (int k = 0; k < 4; ++k) {
      float v = s4[q][k];
      v += __shfl_xor(v, 16, 64);
      v += __shfl_xor(v, 32, 64);
      s4[q][k] = v;
    }
  }

  // ---- softmax over 25 taps, fully in registers (duplicated per cg) ----
  float t[TAPS];
  #pragma unroll
  for (int o = 0; o < TAPS; ++o) t[o] = s4[o >> 2][o & 3] + beff[o];
  float m = t[0];
  #pragma unroll
  for (int o = 1; o < TAPS; ++o) m = fmaxf(m, t[o]);
  float sum = 0.f;
  #pragma unroll
  for (int o = 0; o < TAPS; ++o) { t[o] = __expf(t[o] - m); sum += t[o]; }
  float inv = 1.f / sum;
  #pragma unroll
  for (int o = 0; o < TAPS; ++o) {                   // fold validity mask
    int i = o / 5, j = o % 5;                        // compile-time
    int yy = h + 2 * i - 4, xx = w + 2 * j - 4;
    bool ok = (yy >= 0) & (yy < HH) & (xx >= 0) & (xx < WW);
    t[o] = ok ? t[o] * inv : 0.f;
  }

  // ---- apply: out[c] = sum_tap t[tap] * x[c, tap(h,w)] ----
  float acc[16];
  #pragma unroll
  for (int c = 0; c < 16; ++c) acc[c] = 0.f;
  #pragma unroll
  for (int o = 0; o < TAPS; ++o) {
    int i = o / 5, j = o % 5;
    int yy = h + 2 * i - 4, xx = w + 2 * j - 4;
    bool ok = (yy >= 0) & (yy < HH) & (xx >= 0) & (xx < WW);
    int offt = ok ? yy * WW + xx : 0;                // t[o]==0 masks invalid
    float sv = t[o];
    #pragma unroll
    for (int c = 0; c < 16; ++c)
      acc[c] = fmaf(sv, xc[(size_t)c * HW + offt], acc[c]);
  }
  float* ob = out + ((size_t)b * CH + cg * 16) * HW + hw;
  #pragma unroll
  for (int c = 0; c < 16; ++c) ob[(size_t)c * HW] = acc[c];
}

extern "C" void kernel_launch(void* const* d_in, const int* in_sizes, int n_in,
                              void* d_out, int out_size, void* d_ws, size_t ws_size,
                              hipStream_t stream) {
  const float* x  = (const float*)d_in[0];
  const float* w1 = (const float*)d_in[1];
  const float* b1 = (const float*)d_in[2];
  const float* w2 = (const float*)d_in[3];
  const float* b2 = (const float*)d_in[4];
  float* out  = (float*)d_out;
  // Workspace layout (total 40,025 floats = 160,100 B — proven ws footprint):
  float* weff_main = (float*)d_ws;                   // 25*64*24 = 38400
  float* weff_tail = weff_main + TAPS * CH * GROW;   // +1600
  float* beff      = weff_tail + TAPS * CH;          // +25

  weff_kernel<<<(CH * TAPS + 255) / 256, 256, 0, stream>>>(
      w1, b1, w2, b2, weff_main, weff_tail, beff);
  picanet_main<<<NP / 64, 256, 0, stream>>>(x, weff_main, weff_tail, beff, out);
}